// Round 9
// baseline (382.732 us; speedup 1.0000x reference)
//
#include <hip/hip_runtime.h>
#include <hip/hip_bf16.h>

#define N_TOK 32768
#define DIM 1024
#define OUTD 1024
#define NEXP 64

typedef __attribute__((ext_vector_type(4))) float f32x4;
typedef __attribute__((ext_vector_type(8))) short bf16x8;

__device__ __forceinline__ unsigned short f2bf(float f) {
    unsigned int u = __builtin_bit_cast(unsigned int, f);
    u += 0x7FFFu + ((u >> 16) & 1u);   // RNE
    return (unsigned short)(u >> 16);
}

#define GLOAD16(gp, lp) \
    __builtin_amdgcn_global_load_lds((const __attribute__((address_space(1))) void*)(gp), \
                                     (__attribute__((address_space(3))) void*)(lp), 16, 0, 0)

// ---------------- prep: gate (blocks 0..511) + W transpose (512..2559, coarsened) ----------------
// transpose: each block does 64o x 512d (8 subtiles), register-prefetched, ping-pong LDS,
// ONE barrier per subtile. LDS swizzle identical to R5 (verified conflict-reduced):
//   ts[o*72 + (((d>>3) ^ (o&7) ^ ((o>>3)&7)) << 3) + (d&7)]
__global__ __launch_bounds__(256) void prep_kernel(const float* __restrict__ x,
        const float* __restrict__ gw, const float* __restrict__ gb,
        const float* __restrict__ ew,
        int* __restrict__ sel, int* __restrict__ nflag, int* __restrict__ flags,
        int* __restrict__ counts,
        unsigned short* __restrict__ xb, unsigned short* __restrict__ wt)
{
    __shared__ __align__(16) char smem[18688];
    int tid = threadIdx.x;

    if (blockIdx.x < 512) {
        // ---------------- gate (unchanged, verified) ----------------
        float (*xs)[36]  = (float(*)[36])smem;
        float (*wsm)[36] = (float(*)[36])(smem + 9216);
        int* h = (int*)(smem + 18432);
        if (tid < NEXP) h[tid] = 0;
        int t0 = blockIdx.x * 64;
        int tg = tid >> 4, eg = tid & 15;

        float acc[4][4];
#pragma unroll
        for (int i = 0; i < 4; i++)
#pragma unroll
            for (int j = 0; j < 4; j++) acc[i][j] = 0.f;

        for (int k0 = 0; k0 < DIM; k0 += 32) {
            __syncthreads();
#pragma unroll
            for (int q = 0; q < 2; q++) {
                int cidx = tid + q * 256;
                int r = cidx >> 3, c4 = (cidx & 7) * 4;
                *reinterpret_cast<float4*>(&xs[r][c4]) =
                    *reinterpret_cast<const float4*>(&x[(size_t)(t0 + r) * DIM + k0 + c4]);
                *reinterpret_cast<float4*>(&wsm[r][c4]) =
                    *reinterpret_cast<const float4*>(&gw[(size_t)r * DIM + k0 + c4]);
            }
            __syncthreads();
            if (xb) {
                int r = tid >> 2, cc = (tid & 3) * 8;
                float4 v0 = *reinterpret_cast<const float4*>(&xs[r][cc]);
                float4 v1 = *reinterpret_cast<const float4*>(&xs[r][cc + 4]);
                uint4 p;
                p.x = (unsigned int)f2bf(v0.x) | ((unsigned int)f2bf(v0.y) << 16);
                p.y = (unsigned int)f2bf(v0.z) | ((unsigned int)f2bf(v0.w) << 16);
                p.z = (unsigned int)f2bf(v1.x) | ((unsigned int)f2bf(v1.y) << 16);
                p.w = (unsigned int)f2bf(v1.z) | ((unsigned int)f2bf(v1.w) << 16);
                *reinterpret_cast<uint4*>(&xb[(size_t)(t0 + r) * DIM + k0 + cc]) = p;
            }
#pragma unroll
            for (int kk4 = 0; kk4 < 8; kk4++) {
                float4 xv[4], wv[4];
#pragma unroll
                for (int i = 0; i < 4; i++)
                    xv[i] = *reinterpret_cast<const float4*>(&xs[tg + 16 * i][kk4 * 4]);
#pragma unroll
                for (int j = 0; j < 4; j++)
                    wv[j] = *reinterpret_cast<const float4*>(&wsm[eg + 16 * j][kk4 * 4]);
#pragma unroll
                for (int i = 0; i < 4; i++)
#pragma unroll
                    for (int j = 0; j < 4; j++) {
                        acc[i][j] = fmaf(xv[i].x, wv[j].x, acc[i][j]);
                        acc[i][j] = fmaf(xv[i].y, wv[j].y, acc[i][j]);
                        acc[i][j] = fmaf(xv[i].z, wv[j].z, acc[i][j]);
                        acc[i][j] = fmaf(xv[i].w, wv[j].w, acc[i][j]);
                    }
            }
        }
#pragma unroll
        for (int j = 0; j < 4; j++) {
            float b = gb[eg + 16 * j];
#pragma unroll
            for (int i = 0; i < 4; i++) acc[i][j] += b;
        }
#pragma unroll
        for (int i = 0; i < 4; i++) {
            float m1 = -1e30f, m2 = -1e30f; int e1 = 0;
#pragma unroll
            for (int j = 0; j < 4; j++) {
                float v = acc[i][j]; int e = eg + 16 * j;
                if (v > m1) { m2 = m1; m1 = v; e1 = e; }
                else if (v > m2) m2 = v;
            }
#pragma unroll
            for (int d = 1; d < 16; d <<= 1) {
                float om1 = __shfl_xor(m1, d, 16);
                float om2 = __shfl_xor(m2, d, 16);
                int   oe1 = __shfl_xor(e1, d, 16);
                if (om1 > m1 || (om1 == m1 && oe1 < e1)) {
                    m2 = fmaxf(om2, m1); m1 = om1; e1 = oe1;
                } else {
                    m2 = fmaxf(m2, om1);
                }
            }
            if (eg == 0) {
                int t = t0 + tg + 16 * i;
                sel[t] = e1;
                atomicAdd(&h[e1], 1);
                if (m1 - m2 < 1e-3f) {
                    int idx = atomicAdd(nflag, 1);
                    if (idx < 4096) flags[idx] = t;
                }
            }
        }
        __syncthreads();
        if (tid < NEXP && h[tid]) atomicAdd(&counts[tid], h[tid]);
    } else {
        // ---------------- W transpose, coarsened ----------------
        if (!wt) return;
        unsigned short* ts0 = (unsigned short*)smem;            // [64][72]
        unsigned short* ts1 = (unsigned short*)(smem + 9216);
        int lin = blockIdx.x - 512;        // 0..2047
        int e = lin >> 5;
        int d0 = ((lin >> 4) & 1) * 512;
        int o0 = (lin & 15) * 64;
        const float* src = ew + (size_t)e * (DIM * OUTD);
        unsigned short* dst = wt + (size_t)e * (DIM * OUTD);
        int og = tid & 7;        // o-octet (write phase)
        int dl = tid >> 3;       // 0..31 (write phase d row)
        int dc = tid & 7;        // d-octet (read phase)
        int ol = tid >> 3;       // 0..31 (read phase o row)

        // prefetch subtile 0
        float4 c0, c1, c2, c3;
        {
            const float* sr0 = &src[(size_t)(d0 + dl) * OUTD + o0 + og * 8];
            const float* sr1 = &src[(size_t)(d0 + dl + 32) * OUTD + o0 + og * 8];
            c0 = *reinterpret_cast<const float4*>(sr0);
            c1 = *reinterpret_cast<const float4*>(sr0 + 4);
            c2 = *reinterpret_cast<const float4*>(sr1);
            c3 = *reinterpret_cast<const float4*>(sr1 + 4);
        }
#pragma unroll
        for (int s = 0; s < 8; ++s) {
            float4 n0 = c0, n1 = c1, n2 = c2, n3 = c3;
            if (s < 7) {
                int dsn = d0 + (s + 1) * 64;
                const float* sr0 = &src[(size_t)(dsn + dl) * OUTD + o0 + og * 8];
                const float* sr1 = &src[(size_t)(dsn + dl + 32) * OUTD + o0 + og * 8];
                n0 = *reinterpret_cast<const float4*>(sr0);
                n1 = *reinterpret_cast<const float4*>(sr0 + 4);
                n2 = *reinterpret_cast<const float4*>(sr1);
                n3 = *reinterpret_cast<const float4*>(sr1 + 4);
            }
            unsigned short* tsb = (s & 1) ? ts1 : ts0;
            // write phase: rows dl and dl+32 of this 64x64 subtile
#pragma unroll
            for (int half = 0; half < 2; ++half) {
                int dLoc = dl + 32 * half;
                float4 va = half ? c2 : c0;
                float4 vb = half ? c3 : c1;
                unsigned short b[8] = { f2bf(va.x), f2bf(va.y), f2bf(va.z), f2bf(va.w),
                                        f2bf(vb.x), f2bf(vb.y), f2bf(vb.z), f2bf(vb.w) };
                int dg = dLoc >> 3, dr = dLoc & 7;
#pragma unroll
                for (int k = 0; k < 8; k++) {
                    int o = og * 8 + k;
                    int key = (o & 7) ^ ((o >> 3) & 7);
                    tsb[o * 72 + ((dg ^ key) << 3) + dr] = b[k];
                }
            }
            __syncthreads();
            // read phase: write out transposed (coalesced 128B per o-row)
            int ds0 = d0 + s * 64;
#pragma unroll
            for (int i = 0; i < 2; i++) {
                int o = ol + 32 * i;
                int key = (o & 7) ^ ((o >> 3) & 7);
                uint4 v = *reinterpret_cast<const uint4*>(&tsb[o * 72 + ((dc ^ key) << 3)]);
                *reinterpret_cast<uint4*>(&dst[(size_t)(o0 + o) * DIM + ds0 + dc * 8]) = v;
            }
            c0 = n0; c1 = n1; c2 = n2; c3 = n3;
        }
    }
}

__global__ __launch_bounds__(64) void gate_fix_kernel(const float* __restrict__ x,
        const float* __restrict__ gw, const float* __restrict__ gb,
        int* __restrict__ sel, const int* __restrict__ nflag, const int* __restrict__ flags,
        int* __restrict__ counts)
{
    int n = *nflag; if (n > 4096) n = 4096;
    int b = blockIdx.x;
    if (b >= n) return;
    int t = flags[b];
    int e = threadIdx.x;
    const float* xr = x + (size_t)t * DIM;
    const float* wr = gw + (size_t)e * DIM;
    double acc = (double)gb[e];
    for (int k = 0; k < DIM; k += 4) {
        acc += (double)xr[k]   * (double)wr[k];
        acc += (double)xr[k+1] * (double)wr[k+1];
        acc += (double)xr[k+2] * (double)wr[k+2];
        acc += (double)xr[k+3] * (double)wr[k+3];
    }
    double m1 = acc; int e1 = e;
#pragma unroll
    for (int d = 1; d < 64; d <<= 1) {
        double om1 = __shfl_xor(m1, d, 64);
        int   oe1  = __shfl_xor(e1, d, 64);
        if (om1 > m1 || (om1 == m1 && oe1 < e1)) { m1 = om1; e1 = oe1; }
    }
    if (e == 0) {
        int eOld = sel[t];
        if (eOld != e1) {
            sel[t] = e1;
            atomicSub(&counts[eOld], 1);
            atomicAdd(&counts[e1], 1);
        }
    }
}

__global__ void sched_kernel(const int* __restrict__ counts, int* __restrict__ offsets,
                             int* __restrict__ schedE, int* __restrict__ schedR,
                             int* __restrict__ totalRB, int rowsShift)
{
    int e = threadIdx.x;
    int c = counts[e];
    int v = c;
#pragma unroll
    for (int d = 1; d < 64; d <<= 1) { int y = __shfl_up(v, d, 64); if (e >= d) v += y; }
    offsets[e] = v - c;
    if (e == 63) offsets[NEXP] = v;
    int rows = 1 << rowsShift;
    int nb = (c + rows - 1) >> rowsShift;
    int rbv = nb;
#pragma unroll
    for (int d = 1; d < 64; d <<= 1) { int y = __shfl_up(rbv, d, 64); if (e >= d) rbv += y; }
    int rbBase = rbv - nb;
    for (int i = 0; i < nb; i++) { schedE[rbBase + i] = e; schedR[rbBase + i] = i << rowsShift; }
    if (e == 63) *totalRB = rbv;
}

__global__ __launch_bounds__(256) void scatter_kernel(const int* __restrict__ sel,
        const int* __restrict__ offsets, int* __restrict__ cursor, int* __restrict__ perm)
{
    int t = blockIdx.x * 256 + threadIdx.x;
    int e = sel[t];
    int pos = offsets[e] + atomicAdd(&cursor[e], 1);
    perm[pos] = t;
}

// ---------------- grouped expert GEMM, 256x128x32 bf16 MFMA, ring-3, 2 blocks/CU ----------------
// LDS 72 KB (3 bufs) -> 2 blocks/CU (144 <= 160). Per iter: ONE barrier:
//   { vmcnt(3) [tile t landed own-wave]; s_barrier [publish]; stage(t+2 -> buf (t-1)%3,
//     safe: last read at iter t-1, published by this barrier]; compute(t) }
// Counted vmcnt only; loads get ~2.5 compute phases of slack.
__global__ __launch_bounds__(512, 4) void moe_gemm7(
        const unsigned short* __restrict__ xb, const unsigned short* __restrict__ wt,
        const float* __restrict__ eb,
        const int* __restrict__ perm, const int* __restrict__ offsets,
        const int* __restrict__ counts, const int* __restrict__ schedE,
        const int* __restrict__ schedR, const int* __restrict__ totalRB,
        float* __restrict__ out)
{
    int idx = blockIdx.x;
    int xcd = idx & 7;
    int s = idx >> 3;
    int cb = s & 7;                 // 8 col-blocks of 128
    int rb = (s >> 3) * 8 + xcd;
    if (rb >= *totalRB) return;
    int e = schedE[rb], r0 = schedR[rb];
    int cnt = counts[e], base = offsets[e];

    __shared__ __align__(16) unsigned short As[24576];   // 3 bufs x 256 x 32 (48 KB)
    __shared__ __align__(16) unsigned short Bs[12288];   // 3 bufs x 128 x 32 (24 KB)

    int tid = threadIdx.x;
    int lane = tid & 63;
    int wv = tid >> 6;
    int wr = wv >> 1, wc = wv & 1;      // 4 row-groups x 2 col-groups
    int lr = lane & 15, lg = lane >> 4;

    int rowS = tid >> 2;
    int koff = ((tid & 3) ^ ((tid >> 3) & 3)) * 8;   // proven 0-conflict swizzle
    int rA1 = r0 + rowS, rA2 = r0 + 128 + rowS;
    int tokA1 = (rA1 < cnt) ? perm[base + rA1] : 0;
    int tokA2 = (rA2 < cnt) ? perm[base + rA2] : 0;

    const unsigned short* wte = wt + ((size_t)e << 20);
    const unsigned short* aSrc1 = xb + (size_t)tokA1 * DIM + koff;
    const unsigned short* aSrc2 = xb + (size_t)tokA2 * DIM + koff;
    const unsigned short* bSrc1 = wte + (size_t)(cb * 128 + rowS) * DIM + koff;

    unsigned short* AsQ0 = As + wv * 512;          // wave-uniform (+lane*16B by HW)
    unsigned short* AsQ1 = As + 4096 + wv * 512;
    unsigned short* BsQ0 = Bs + wv * 512;

    f32x4 acc[4][4];
#pragma unroll
    for (int m = 0; m < 4; m++)
#pragma unroll
        for (int n = 0; n < 4; n++)
#pragma unroll
            for (int c = 0; c < 4; c++) acc[m][n][c] = 0.f;

    const char* Asc = (const char*)As;
    const char* Bsc = (const char*)Bs;
    int fko = (lg ^ ((lr >> 1) & 3)) * 16;

    auto stage = [&](int buf, int k0) {
        GLOAD16(aSrc1 + k0, AsQ0 + buf * 8192);
        GLOAD16(aSrc2 + k0, AsQ1 + buf * 8192);
        GLOAD16(bSrc1 + k0, BsQ0 + buf * 4096);
    };
    auto compute = [&](int buf) {
        int aoff = buf * 16384;  // bytes
        int boff = buf * 8192;
        bf16x8 bfr[4];
#pragma unroll
        for (int n = 0; n < 4; n++) {
            int row = wc * 64 + n * 16 + lr;
            bfr[n] = *reinterpret_cast<const bf16x8*>(Bsc + boff + (row << 6) + fko);
        }
        __builtin_amdgcn_s_setprio(1);
#pragma unroll
        for (int m = 0; m < 4; m++) {
            int row = wr * 64 + m * 16 + lr;
            bf16x8 afr = *reinterpret_cast<const bf16x8*>(Asc + aoff + (row << 6) + fko);
#pragma unroll
            for (int n = 0; n < 4; n++)
                acc[m][n] = __builtin_amdgcn_mfma_f32_16x16x32_bf16(afr, bfr[n], acc[m][n], 0, 0, 0);
        }
        __builtin_amdgcn_s_setprio(0);
    };

    // prologue: tiles 0,1 in flight (6 loads)
    stage(0, 0);
    stage(1, 32);

    int cbuf = 0, sbuf = 2;
#pragma unroll 1
    for (int t = 0; t < 30; ++t) {
        asm volatile("s_waitcnt vmcnt(3)" ::: "memory");   // tile t landed (own-wave)
        __builtin_amdgcn_s_barrier();                      // publish; frees buf (t-1)%3
        stage(sbuf, (t + 2) * 32);                         // tile t+2 -> freed buf
        compute(cbuf);                                     // tile t
        cbuf = (cbuf == 2) ? 0 : cbuf + 1;
        sbuf = (sbuf == 2) ? 0 : sbuf + 1;
    }
    asm volatile("s_waitcnt vmcnt(3)" ::: "memory");       // tile 30
    __builtin_amdgcn_s_barrier();
    compute(cbuf);
    cbuf = (cbuf == 2) ? 0 : cbuf + 1;
    asm volatile("s_waitcnt vmcnt(0)" ::: "memory");       // tile 31
    __builtin_amdgcn_s_barrier();
    compute(cbuf);

    // epilogue: C/D layout col = lane&15, row = (lane>>4)*4 + i
    float bias[4];
#pragma unroll
    for (int n = 0; n < 4; n++)
        bias[n] = eb[e * OUTD + cb * 128 + wc * 64 + n * 16 + lr];
#pragma unroll
    for (int m = 0; m < 4; m++) {
        int rowLoc = wr * 64 + m * 16 + lg * 4;
#pragma unroll
        for (int i2 = 0; i2 < 4; i2++) {
            int r = r0 + rowLoc + i2;
            if (r < cnt) {
                int tk = perm[base + r];
#pragma unroll
                for (int n = 0; n < 4; n++) {
                    int oc = cb * 128 + wc * 64 + n * 16 + lr;
                    out[(size_t)tk * OUTD + oc] = acc[m][n][i2] + bias[n];
                }
            }
        }
    }
}

// ---------------- legacy (R1) GEMM — fallback if ws too small ----------------
__global__ __launch_bounds__(256) void moe_gemm_legacy(const float* __restrict__ x,
        const float* __restrict__ ew, const float* __restrict__ eb,
        const int* __restrict__ perm, const int* __restrict__ offsets,
        const int* __restrict__ counts, const int* __restrict__ schedE,
        const int* __restrict__ schedR, const int* __restrict__ totalRB,
        float* __restrict__ out)
{
    int rb = blockIdx.x;
    if (rb >= *totalRB) return;
    int cb = blockIdx.y;
    int e = schedE[rb], r0 = schedR[rb];
    int cnt = counts[e], base = offsets[e];

    __shared__ __align__(16) unsigned short As[128][40];
    __shared__ __align__(16) unsigned short Bs[128][40];
    __shared__ int toks[128];

    int tid = threadIdx.x;
    if (tid < 128) {
        int r = r0 + tid;
        toks[tid] = (r < cnt) ? perm[base + r] : -1;
    }
    __syncthreads();

    int lane = tid & 63;
    int wave = tid >> 6;
    int wr = wave >> 1, wc = wave & 1;
    int lr = lane & 15, lg = lane >> 4;

    f32x4 acc[4][4];
#pragma unroll
    for (int m = 0; m < 4; m++)
#pragma unroll
        for (int n = 0; n < 4; n++)
#pragma unroll
            for (int c = 0; c < 4; c++) acc[m][n][c] = 0.f;

    int aRow[4]; int aTok[4];
#pragma unroll
    for (int q = 0; q < 4; q++) {
        aRow[q] = (tid >> 3) + q * 32;
        int tk = toks[aRow[q]];
        aTok[q] = (tk < 0) ? 0 : tk;
    }
    int ac4 = tid & 7;
    int d0 = (tid >> 5) * 4;
    int o_lane = tid & 31;
    const float* wb = ew + (size_t)e * (DIM * OUTD) + (size_t)cb * 128;

    for (int k0 = 0; k0 < DIM; k0 += 32) {
        float4 av[4];
#pragma unroll
        for (int q = 0; q < 4; q++)
            av[q] = *reinterpret_cast<const float4*>(&x[(size_t)aTok[q] * DIM + k0 + ac4 * 4]);
        float bv[4][4];
#pragma unroll
        for (int i2 = 0; i2 < 4; i2++)
#pragma unroll
            for (int j = 0; j < 4; j++)
                bv[i2][j] = wb[(size_t)(k0 + d0 + i2) * OUTD + o_lane + 32 * j];

        __syncthreads();
#pragma unroll
        for (int q = 0; q < 4; q++) {
            uint2 p;
            p.x = (unsigned int)f2bf(av[q].x) | ((unsigned int)f2bf(av[q].y) << 16);
            p.y = (unsigned int)f2bf(av[q].z) | ((unsigned int)f2bf(av[q].w) << 16);
            *reinterpret_cast<uint2*>(&As[aRow[q]][ac4 * 4]) = p;
        }
#pragma unroll
        for (int j = 0; j < 4; j++) {
            uint2 p;
            p.x = (unsigned int)f2bf(bv[0][j]) | ((unsigned int)f2bf(bv[1][j]) << 16);
            p.y = (unsigned int)f2bf(bv[2][j]) | ((unsigned int)f2bf(bv[3][j]) << 16);
            *reinterpret_cast<uint2*>(&Bs[o_lane + 32 * j][d0]) = p;
        }
        __syncthreads();

        bf16x8 bfr[4];
#pragma unroll
        for (int n = 0; n < 4; n++)
            bfr[n] = *reinterpret_cast<const bf16x8*>(&Bs[wc * 64 + n * 16 + lr][lg * 8]);
#pragma unroll
        for (int m = 0; m < 4; m++) {
            bf16x8 afr = *reinterpret_cast<const bf16x8*>(&As[wr * 64 + m * 16 + lr][lg * 8]);
#pragma unroll
            for (int n = 0; n < 4; n++)
                acc[m][n] = __builtin_amdgcn_mfma_f32_16x16x32_bf16(afr, bfr[n], acc[m][n], 0, 0, 0);
        }
    }

#pragma unroll
    for (int n = 0; n < 4; n++) {
        int oc = cb * 128 + wc * 64 + n * 16 + lr;
        float bias = eb[e * OUTD + oc];
#pragma unroll
        for (int m = 0; m < 4; m++) {
#pragma unroll
            for (int i2 = 0; i2 < 4; i2++) {
                int rr = wr * 64 + m * 16 + lg * 4 + i2;
                int tk = toks[rr];
                if (tk >= 0)
                    out[(size_t)tk * OUTD + oc] = acc[m][n][i2] + bias;
            }
        }
    }
}

extern "C" void kernel_launch(void* const* d_in, const int* in_sizes, int n_in,
                              void* d_out, int out_size, void* d_ws, size_t ws_size,
                              hipStream_t stream)
{
    const float* x  = (const float*)d_in[0];
    const float* gw = (const float*)d_in[1];
    const float* gb = (const float*)d_in[2];
    const float* ew = (const float*)d_in[3];
    const float* eb = (const float*)d_in[4];
    float* out = (float*)d_out;

    char* ws = (char*)d_ws;
    int* counts  = (int*)(ws + 0);
    int* cursor  = (int*)(ws + 256);
    int* offsets = (int*)(ws + 512);
    int* totalRB = (int*)(ws + 1024);
    int* nflag   = (int*)(ws + 1028);
    int* flags   = (int*)(ws + 1032);
    int* schedE  = (int*)(ws + 20480);
    int* schedR  = (int*)(ws + 22528);
    int* sel     = (int*)(ws + 24576);
    int* perm    = (int*)(ws + 155648);

    const size_t WT_OFF   = (size_t)1 << 20;
    const size_t WT_BYTES = (size_t)NEXP * DIM * OUTD * 2;   // 128 MiB
    const size_t XB_OFF   = WT_OFF + WT_BYTES;
    const size_t XB_BYTES = (size_t)N_TOK * DIM * 2;         // 64 MiB
    int mode = (ws_size >= XB_OFF + XB_BYTES) ? 2 : 0;
    unsigned short* wt = (mode == 2) ? (unsigned short*)(ws + WT_OFF) : nullptr;
    unsigned short* xb = (mode == 2) ? (unsigned short*)(ws + XB_OFF) : nullptr;

    hipMemsetAsync(ws, 0, 2048, stream);

    prep_kernel<<<dim3(512 + ((mode == 2) ? 2048 : 0)), 256, 0, stream>>>(
        x, gw, gb, ew, sel, nflag, flags, counts, xb, wt);
    gate_fix_kernel<<<dim3(4096), 64, 0, stream>>>(x, gw, gb, sel, nflag, flags, counts);
    sched_kernel<<<dim3(1), 64, 0, stream>>>(counts, offsets, schedE, schedR, totalRB,
                                             (mode == 2) ? 8 : 7);
    scatter_kernel<<<dim3(N_TOK / 256), 256, 0, stream>>>(sel, offsets, cursor, perm);

    if (mode == 2)
        moe_gemm7<<<dim3(1536), 512, 0, stream>>>(xb, wt, eb, perm, offsets, counts,
                                                  schedE, schedR, totalRB, out);
    else
        moe_gemm_legacy<<<dim3(320, 8), 256, 0, stream>>>(x, ew, eb, perm, offsets, counts,
                                                          schedE, schedR, totalRB, out);
}

// Round 10
// 377.438 us; speedup vs baseline: 1.0140x; 1.0140x over previous
//
#include <hip/hip_runtime.h>
#include <hip/hip_bf16.h>

#define N_TOK 32768
#define DIM 1024
#define OUTD 1024
#define NEXP 64

typedef __attribute__((ext_vector_type(4))) float f32x4;
typedef __attribute__((ext_vector_type(8))) short bf16x8;

__device__ __forceinline__ unsigned short f2bf(float f) {
    unsigned int u = __builtin_bit_cast(unsigned int, f);
    u += 0x7FFFu + ((u >> 16) & 1u);   // RNE
    return (unsigned short)(u >> 16);
}

__device__ __forceinline__ uint4 pack8(float4 a, float4 b) {
    uint4 p;
    p.x = (unsigned int)f2bf(a.x) | ((unsigned int)f2bf(a.y) << 16);
    p.y = (unsigned int)f2bf(a.z) | ((unsigned int)f2bf(a.w) << 16);
    p.z = (unsigned int)f2bf(b.x) | ((unsigned int)f2bf(b.y) << 16);
    p.w = (unsigned int)f2bf(b.z) | ((unsigned int)f2bf(b.w) << 16);
    return p;
}

#define GLOAD16(gp, lp) \
    __builtin_amdgcn_global_load_lds((const __attribute__((address_space(1))) void*)(gp), \
                                     (__attribute__((address_space(3))) void*)(lp), 16, 0, 0)

// ---------------- prep: MFMA gate (blocks 0..511) + W transpose (512..2559) ----------------
// gate: logits via bf16 MFMA (x and gw staged bf16 with the proven GEMM swizzle);
// fused xb writeout from staging registers. Tokens with top-2 gap < 0.01 (14 sigma of
// bf16 rounding) are flagged for exact fp64 re-resolution.
__global__ __launch_bounds__(256) void prep_kernel(const float* __restrict__ x,
        const float* __restrict__ gw, const float* __restrict__ gb,
        const float* __restrict__ ew,
        int* __restrict__ sel, int* __restrict__ nflag, int* __restrict__ flags,
        int* __restrict__ counts,
        unsigned short* __restrict__ xb, unsigned short* __restrict__ wt)
{
    __shared__ __align__(16) char smem[18688];
    int tid = threadIdx.x;

    if (blockIdx.x < 512) {
        // ---------------- gate via MFMA ----------------
        unsigned short* Ag = (unsigned short*)smem;           // [2][64*32] bf16 (8 KB)
        unsigned short* Bg = (unsigned short*)(smem + 8192);  // [2][64*32] bf16 (8 KB)
        int* h = (int*)(smem + 16384);
        if (tid < NEXP) h[tid] = 0;

        int t0 = blockIdx.x * 64;
        int lane = tid & 63;
        int w = tid >> 6;              // wave 0..3 -> token rows 16w..16w+15
        int lr = lane & 15, lg = lane >> 4;

        // staging: thread -> (row = tid>>2, storage chunk = tid&3); source chunk swizzled
        int rowS = tid >> 2;
        int koffS = (((tid & 3) ^ ((tid >> 3) & 3)) * 8);
        const float* xsrc = x + (size_t)(t0 + rowS) * DIM + koffS;
        const float* wsrc = gw + (size_t)rowS * DIM + koffS;
        unsigned short* xdst = xb ? xb + (size_t)(t0 + rowS) * DIM + koffS : nullptr;

        f32x4 acc[4];
#pragma unroll
        for (int n = 0; n < 4; n++)
#pragma unroll
            for (int c = 0; c < 4; c++) acc[n][c] = 0.f;

        // prologue: stage chunk 0 into buf 0
        float4 v0 = *reinterpret_cast<const float4*>(xsrc);
        float4 v1 = *reinterpret_cast<const float4*>(xsrc + 4);
        float4 v2 = *reinterpret_cast<const float4*>(wsrc);
        float4 v3 = *reinterpret_cast<const float4*>(wsrc + 4);
        {
            uint4 pa = pack8(v0, v1), pb = pack8(v2, v3);
            *reinterpret_cast<uint4*>(&Ag[tid * 8]) = pa;
            *reinterpret_cast<uint4*>(&Bg[tid * 8]) = pb;
            if (xdst) *reinterpret_cast<uint4*>(xdst) = pa;
        }
        __syncthreads();

        const char* Agc = (const char*)Ag;
        const char* Bgc = (const char*)Bg;
        int fko = (lg ^ ((lr >> 1) & 3)) * 16;

#pragma unroll 1
        for (int t = 0; t < 32; ++t) {
            if (t < 31) {                          // prefetch chunk t+1 to regs
                int k0 = (t + 1) * 32;
                v0 = *reinterpret_cast<const float4*>(xsrc + k0);
                v1 = *reinterpret_cast<const float4*>(xsrc + k0 + 4);
                v2 = *reinterpret_cast<const float4*>(wsrc + k0);
                v3 = *reinterpret_cast<const float4*>(wsrc + k0 + 4);
            }
            int boff = (t & 1) * 4096;             // bytes
            bf16x8 afr = *reinterpret_cast<const bf16x8*>(Agc + boff + ((w * 16 + lr) << 6) + fko);
#pragma unroll
            for (int n = 0; n < 4; n++) {
                bf16x8 bfr = *reinterpret_cast<const bf16x8*>(Bgc + boff + ((n * 16 + lr) << 6) + fko);
                acc[n] = __builtin_amdgcn_mfma_f32_16x16x32_bf16(afr, bfr, acc[n], 0, 0, 0);
            }
            if (t < 31) {                          // write chunk t+1 into other buf
                uint4 pa = pack8(v0, v1), pb = pack8(v2, v3);
                int soff = ((t + 1) & 1) * 2048;   // shorts
                *reinterpret_cast<uint4*>(&Ag[soff + tid * 8]) = pa;
                *reinterpret_cast<uint4*>(&Bg[soff + tid * 8]) = pb;
                if (xdst) *reinterpret_cast<uint4*>(xdst + (t + 1) * 32) = pa;
            }
            __syncthreads();
        }

        // epilogue: lane holds rows (16w + lg*4 + i), cols (16n + lr); top-2 per row
        float gbv[4];
#pragma unroll
        for (int n = 0; n < 4; n++) gbv[n] = gb[n * 16 + lr];
#pragma unroll
        for (int i = 0; i < 4; i++) {
            float m1 = -1e30f, m2 = -1e30f; int e1 = 0;
#pragma unroll
            for (int n = 0; n < 4; n++) {
                float v = acc[n][i] + gbv[n];
                if (v > m1) { m2 = m1; m1 = v; e1 = n * 16 + lr; }
                else if (v > m2) m2 = v;
            }
#pragma unroll
            for (int d = 1; d < 16; d <<= 1) {
                float om1 = __shfl_xor(m1, d, 16);
                float om2 = __shfl_xor(m2, d, 16);
                int   oe1 = __shfl_xor(e1, d, 16);
                if (om1 > m1 || (om1 == m1 && oe1 < e1)) {
                    m2 = fmaxf(om2, m1); m1 = om1; e1 = oe1;
                } else {
                    m2 = fmaxf(m2, om1);
                }
            }
            if (lr == 0) {
                int t = t0 + w * 16 + lg * 4 + i;
                sel[t] = e1;
                atomicAdd(&h[e1], 1);
                if (m1 - m2 < 0.01f) {             // 14-sigma bf16-rounding guard
                    int idx = atomicAdd(nflag, 1);
                    if (idx < 16384) flags[idx] = t;
                }
            }
        }
        __syncthreads();
        if (tid < NEXP && h[tid]) atomicAdd(&counts[tid], h[tid]);
    } else {
        // ---------------- W transpose, coarsened (R9, verified) ----------------
        if (!wt) return;
        unsigned short* ts0 = (unsigned short*)smem;            // [64][72]
        unsigned short* ts1 = (unsigned short*)(smem + 9216);
        int lin = blockIdx.x - 512;        // 0..2047
        int e = lin >> 5;
        int d0 = ((lin >> 4) & 1) * 512;
        int o0 = (lin & 15) * 64;
        const float* src = ew + (size_t)e * (DIM * OUTD);
        unsigned short* dst = wt + (size_t)e * (DIM * OUTD);
        int og = tid & 7;
        int dl = tid >> 3;
        int dc = tid & 7;
        int ol = tid >> 3;

        float4 c0, c1, c2, c3;
        {
            const float* sr0 = &src[(size_t)(d0 + dl) * OUTD + o0 + og * 8];
            const float* sr1 = &src[(size_t)(d0 + dl + 32) * OUTD + o0 + og * 8];
            c0 = *reinterpret_cast<const float4*>(sr0);
            c1 = *reinterpret_cast<const float4*>(sr0 + 4);
            c2 = *reinterpret_cast<const float4*>(sr1);
            c3 = *reinterpret_cast<const float4*>(sr1 + 4);
        }
#pragma unroll
        for (int s = 0; s < 8; ++s) {
            float4 n0 = c0, n1 = c1, n2 = c2, n3 = c3;
            if (s < 7) {
                int dsn = d0 + (s + 1) * 64;
                const float* sr0 = &src[(size_t)(dsn + dl) * OUTD + o0 + og * 8];
                const float* sr1 = &src[(size_t)(dsn + dl + 32) * OUTD + o0 + og * 8];
                n0 = *reinterpret_cast<const float4*>(sr0);
                n1 = *reinterpret_cast<const float4*>(sr0 + 4);
                n2 = *reinterpret_cast<const float4*>(sr1);
                n3 = *reinterpret_cast<const float4*>(sr1 + 4);
            }
            unsigned short* tsb = (s & 1) ? ts1 : ts0;
#pragma unroll
            for (int half = 0; half < 2; ++half) {
                int dLoc = dl + 32 * half;
                float4 va = half ? c2 : c0;
                float4 vb = half ? c3 : c1;
                unsigned short b[8] = { f2bf(va.x), f2bf(va.y), f2bf(va.z), f2bf(va.w),
                                        f2bf(vb.x), f2bf(vb.y), f2bf(vb.z), f2bf(vb.w) };
                int dg = dLoc >> 3, dr = dLoc & 7;
#pragma unroll
                for (int k = 0; k < 8; k++) {
                    int o = og * 8 + k;
                    int key = (o & 7) ^ ((o >> 3) & 7);
                    tsb[o * 72 + ((dg ^ key) << 3) + dr] = b[k];
                }
            }
            __syncthreads();
            int ds0 = d0 + s * 64;
#pragma unroll
            for (int i = 0; i < 2; i++) {
                int o = ol + 32 * i;
                int key = (o & 7) ^ ((o >> 3) & 7);
                uint4 v = *reinterpret_cast<const uint4*>(&tsb[o * 72 + ((dc ^ key) << 3)]);
                *reinterpret_cast<uint4*>(&dst[(size_t)(o0 + o) * DIM + ds0 + dc * 8]) = v;
            }
            c0 = n0; c1 = n1; c2 = n2; c3 = n3;
        }
    }
}

// fp64 re-resolution of flagged tokens; patches sel AND counts.
__global__ __launch_bounds__(64) void gate_fix_kernel(const float* __restrict__ x,
        const float* __restrict__ gw, const float* __restrict__ gb,
        int* __restrict__ sel, const int* __restrict__ nflag, const int* __restrict__ flags,
        int* __restrict__ counts)
{
    int n = *nflag; if (n > 16384) n = 16384;
    int b = blockIdx.x;
    if (b >= n) return;
    int t = flags[b];
    int e = threadIdx.x;
    const float* xr = x + (size_t)t * DIM;
    const float* wr = gw + (size_t)e * DIM;
    double acc = (double)gb[e];
    for (int k = 0; k < DIM; k += 4) {
        acc += (double)xr[k]   * (double)wr[k];
        acc += (double)xr[k+1] * (double)wr[k+1];
        acc += (double)xr[k+2] * (double)wr[k+2];
        acc += (double)xr[k+3] * (double)wr[k+3];
    }
    double m1 = acc; int e1 = e;
#pragma unroll
    for (int d = 1; d < 64; d <<= 1) {
        double om1 = __shfl_xor(m1, d, 64);
        int   oe1  = __shfl_xor(e1, d, 64);
        if (om1 > m1 || (om1 == m1 && oe1 < e1)) { m1 = om1; e1 = oe1; }
    }
    if (e == 0) {
        int eOld = sel[t];
        if (eOld != e1) {
            sel[t] = e1;
            atomicSub(&counts[eOld], 1);
            atomicAdd(&counts[e1], 1);
        }
    }
}

__global__ void sched_kernel(const int* __restrict__ counts, int* __restrict__ offsets,
                             int* __restrict__ schedE, int* __restrict__ schedR,
                             int* __restrict__ totalRB, int rowsShift)
{
    int e = threadIdx.x;
    int c = counts[e];
    int v = c;
#pragma unroll
    for (int d = 1; d < 64; d <<= 1) { int y = __shfl_up(v, d, 64); if (e >= d) v += y; }
    offsets[e] = v - c;
    if (e == 63) offsets[NEXP] = v;
    int rows = 1 << rowsShift;
    int nb = (c + rows - 1) >> rowsShift;
    int rbv = nb;
#pragma unroll
    for (int d = 1; d < 64; d <<= 1) { int y = __shfl_up(rbv, d, 64); if (e >= d) rbv += y; }
    int rbBase = rbv - nb;
    for (int i = 0; i < nb; i++) { schedE[rbBase + i] = e; schedR[rbBase + i] = i << rowsShift; }
    if (e == 63) *totalRB = rbv;
}

__global__ __launch_bounds__(256) void scatter_kernel(const int* __restrict__ sel,
        const int* __restrict__ offsets, int* __restrict__ cursor, int* __restrict__ perm)
{
    int t = blockIdx.x * 256 + threadIdx.x;
    int e = sel[t];
    int pos = offsets[e] + atomicAdd(&cursor[e], 1);
    perm[pos] = t;
}

// ---------------- grouped expert GEMM, 256x128x32 bf16 MFMA, ring-3, 2 blocks/CU ----------------
// (R9 structure, verified)
__global__ __launch_bounds__(512, 4) void moe_gemm7(
        const unsigned short* __restrict__ xb, const unsigned short* __restrict__ wt,
        const float* __restrict__ eb,
        const int* __restrict__ perm, const int* __restrict__ offsets,
        const int* __restrict__ counts, const int* __restrict__ schedE,
        const int* __restrict__ schedR, const int* __restrict__ totalRB,
        float* __restrict__ out)
{
    int idx = blockIdx.x;
    int xcd = idx & 7;
    int s = idx >> 3;
    int cb = s & 7;
    int rb = (s >> 3) * 8 + xcd;
    if (rb >= *totalRB) return;
    int e = schedE[rb], r0 = schedR[rb];
    int cnt = counts[e], base = offsets[e];

    __shared__ __align__(16) unsigned short As[24576];   // 3 bufs x 256 x 32
    __shared__ __align__(16) unsigned short Bs[12288];   // 3 bufs x 128 x 32

    int tid = threadIdx.x;
    int lane = tid & 63;
    int wv = tid >> 6;
    int wr = wv >> 1, wc = wv & 1;
    int lr = lane & 15, lg = lane >> 4;

    int rowS = tid >> 2;
    int koff = ((tid & 3) ^ ((tid >> 3) & 3)) * 8;
    int rA1 = r0 + rowS, rA2 = r0 + 128 + rowS;
    int tokA1 = (rA1 < cnt) ? perm[base + rA1] : 0;
    int tokA2 = (rA2 < cnt) ? perm[base + rA2] : 0;

    const unsigned short* wte = wt + ((size_t)e << 20);
    const unsigned short* aSrc1 = xb + (size_t)tokA1 * DIM + koff;
    const unsigned short* aSrc2 = xb + (size_t)tokA2 * DIM + koff;
    const unsigned short* bSrc1 = wte + (size_t)(cb * 128 + rowS) * DIM + koff;

    unsigned short* AsQ0 = As + wv * 512;
    unsigned short* AsQ1 = As + 4096 + wv * 512;
    unsigned short* BsQ0 = Bs + wv * 512;

    f32x4 acc[4][4];
#pragma unroll
    for (int m = 0; m < 4; m++)
#pragma unroll
        for (int n = 0; n < 4; n++)
#pragma unroll
            for (int c = 0; c < 4; c++) acc[m][n][c] = 0.f;

    const char* Asc = (const char*)As;
    const char* Bsc = (const char*)Bs;
    int fko = (lg ^ ((lr >> 1) & 3)) * 16;

    auto stage = [&](int buf, int k0) {
        GLOAD16(aSrc1 + k0, AsQ0 + buf * 8192);
        GLOAD16(aSrc2 + k0, AsQ1 + buf * 8192);
        GLOAD16(bSrc1 + k0, BsQ0 + buf * 4096);
    };
    auto compute = [&](int buf) {
        int aoff = buf * 16384;
        int boff = buf * 8192;
        bf16x8 bfr[4];
#pragma unroll
        for (int n = 0; n < 4; n++) {
            int row = wc * 64 + n * 16 + lr;
            bfr[n] = *reinterpret_cast<const bf16x8*>(Bsc + boff + (row << 6) + fko);
        }
        __builtin_amdgcn_s_setprio(1);
#pragma unroll
        for (int m = 0; m < 4; m++) {
            int row = wr * 64 + m * 16 + lr;
            bf16x8 afr = *reinterpret_cast<const bf16x8*>(Asc + aoff + (row << 6) + fko);
#pragma unroll
            for (int n = 0; n < 4; n++)
                acc[m][n] = __builtin_amdgcn_mfma_f32_16x16x32_bf16(afr, bfr[n], acc[m][n], 0, 0, 0);
        }
        __builtin_amdgcn_s_setprio(0);
    };

    stage(0, 0);
    stage(1, 32);

    int cbuf = 0, sbuf = 2;
#pragma unroll 1
    for (int t = 0; t < 30; ++t) {
        asm volatile("s_waitcnt vmcnt(3)" ::: "memory");
        __builtin_amdgcn_s_barrier();
        stage(sbuf, (t + 2) * 32);
        compute(cbuf);
        cbuf = (cbuf == 2) ? 0 : cbuf + 1;
        sbuf = (sbuf == 2) ? 0 : sbuf + 1;
    }
    asm volatile("s_waitcnt vmcnt(3)" ::: "memory");
    __builtin_amdgcn_s_barrier();
    compute(cbuf);
    cbuf = (cbuf == 2) ? 0 : cbuf + 1;
    asm volatile("s_waitcnt vmcnt(0)" ::: "memory");
    __builtin_amdgcn_s_barrier();
    compute(cbuf);

    float bias[4];
#pragma unroll
    for (int n = 0; n < 4; n++)
        bias[n] = eb[e * OUTD + cb * 128 + wc * 64 + n * 16 + lr];
#pragma unroll
    for (int m = 0; m < 4; m++) {
        int rowLoc = wr * 64 + m * 16 + lg * 4;
#pragma unroll
        for (int i2 = 0; i2 < 4; i2++) {
            int r = r0 + rowLoc + i2;
            if (r < cnt) {
                int tk = perm[base + r];
#pragma unroll
                for (int n = 0; n < 4; n++) {
                    int oc = cb * 128 + wc * 64 + n * 16 + lr;
                    out[(size_t)tk * OUTD + oc] = acc[m][n][i2] + bias[n];
                }
            }
        }
    }
}

// ---------------- legacy (R1) GEMM — fallback if ws too small ----------------
__global__ __launch_bounds__(256) void moe_gemm_legacy(const float* __restrict__ x,
        const float* __restrict__ ew, const float* __restrict__ eb,
        const int* __restrict__ perm, const int* __restrict__ offsets,
        const int* __restrict__ counts, const int* __restrict__ schedE,
        const int* __restrict__ schedR, const int* __restrict__ totalRB,
        float* __restrict__ out)
{
    int rb = blockIdx.x;
    if (rb >= *totalRB) return;
    int cb = blockIdx.y;
    int e = schedE[rb], r0 = schedR[rb];
    int cnt = counts[e], base = offsets[e];

    __shared__ __align__(16) unsigned short As[128][40];
    __shared__ __align__(16) unsigned short Bs[128][40];
    __shared__ int toks[128];

    int tid = threadIdx.x;
    if (tid < 128) {
        int r = r0 + tid;
        toks[tid] = (r < cnt) ? perm[base + r] : -1;
    }
    __syncthreads();

    int lane = tid & 63;
    int wave = tid >> 6;
    int wr = wave >> 1, wc = wave & 1;
    int lr = lane & 15, lg = lane >> 4;

    f32x4 acc[4][4];
#pragma unroll
    for (int m = 0; m < 4; m++)
#pragma unroll
        for (int n = 0; n < 4; n++)
#pragma unroll
            for (int c = 0; c < 4; c++) acc[m][n][c] = 0.f;

    int aRow[4]; int aTok[4];
#pragma unroll
    for (int q = 0; q < 4; q++) {
        aRow[q] = (tid >> 3) + q * 32;
        int tk = toks[aRow[q]];
        aTok[q] = (tk < 0) ? 0 : tk;
    }
    int ac4 = tid & 7;
    int d0 = (tid >> 5) * 4;
    int o_lane = tid & 31;
    const float* wb = ew + (size_t)e * (DIM * OUTD) + (size_t)cb * 128;

    for (int k0 = 0; k0 < DIM; k0 += 32) {
        float4 av[4];
#pragma unroll
        for (int q = 0; q < 4; q++)
            av[q] = *reinterpret_cast<const float4*>(&x[(size_t)aTok[q] * DIM + k0 + ac4 * 4]);
        float bv[4][4];
#pragma unroll
        for (int i2 = 0; i2 < 4; i2++)
#pragma unroll
            for (int j = 0; j < 4; j++)
                bv[i2][j] = wb[(size_t)(k0 + d0 + i2) * OUTD + o_lane + 32 * j];

        __syncthreads();
#pragma unroll
        for (int q = 0; q < 4; q++) {
            uint2 p;
            p.x = (unsigned int)f2bf(av[q].x) | ((unsigned int)f2bf(av[q].y) << 16);
            p.y = (unsigned int)f2bf(av[q].z) | ((unsigned int)f2bf(av[q].w) << 16);
            *reinterpret_cast<uint2*>(&As[aRow[q]][ac4 * 4]) = p;
        }
#pragma unroll
        for (int j = 0; j < 4; j++) {
            uint2 p;
            p.x = (unsigned int)f2bf(bv[0][j]) | ((unsigned int)f2bf(bv[1][j]) << 16);
            p.y = (unsigned int)f2bf(bv[2][j]) | ((unsigned int)f2bf(bv[3][j]) << 16);
            *reinterpret_cast<uint2*>(&Bs[o_lane + 32 * j][d0]) = p;
        }
        __syncthreads();

        bf16x8 bfr[4];
#pragma unroll
        for (int n = 0; n < 4; n++)
            bfr[n] = *reinterpret_cast<const bf16x8*>(&Bs[wc * 64 + n * 16 + lr][lg * 8]);
#pragma unroll
        for (int m = 0; m < 4; m++) {
            bf16x8 afr = *reinterpret_cast<const bf16x8*>(&As[wr * 64 + m * 16 + lr][lg * 8]);
#pragma unroll
            for (int n = 0; n < 4; n++)
                acc[m][n] = __builtin_amdgcn_mfma_f32_16x16x32_bf16(afr, bfr[n], acc[m][n], 0, 0, 0);
        }
    }

#pragma unroll
    for (int n = 0; n < 4; n++) {
        int oc = cb * 128 + wc * 64 + n * 16 + lr;
        float bias = eb[e * OUTD + oc];
#pragma unroll
        for (int m = 0; m < 4; m++) {
#pragma unroll
            for (int i2 = 0; i2 < 4; i2++) {
                int rr = wr * 64 + m * 16 + lg * 4 + i2;
                int tk = toks[rr];
                if (tk >= 0)
                    out[(size_t)tk * OUTD + oc] = acc[m][n][i2] + bias;
            }
        }
    }
}

extern "C" void kernel_launch(void* const* d_in, const int* in_sizes, int n_in,
                              void* d_out, int out_size, void* d_ws, size_t ws_size,
                              hipStream_t stream)
{
    const float* x  = (const float*)d_in[0];
    const float* gw = (const float*)d_in[1];
    const float* gb = (const float*)d_in[2];
    const float* ew = (const float*)d_in[3];
    const float* eb = (const float*)d_in[4];
    float* out = (float*)d_out;

    char* ws = (char*)d_ws;
    int* counts  = (int*)(ws + 0);
    int* cursor  = (int*)(ws + 256);
    int* offsets = (int*)(ws + 512);
    int* totalRB = (int*)(ws + 1024);
    int* nflag   = (int*)(ws + 1028);
    int* schedE  = (int*)(ws + 2048);
    int* schedR  = (int*)(ws + 4096);
    int* flags   = (int*)(ws + 8192);      // 16384 ints (64 KB)
    int* sel     = (int*)(ws + 131072);    // 128 KB
    int* perm    = (int*)(ws + 262144);    // 128 KB

    const size_t WT_OFF   = (size_t)1 << 20;
    const size_t WT_BYTES = (size_t)NEXP * DIM * OUTD * 2;   // 128 MiB
    const size_t XB_OFF   = WT_OFF + WT_BYTES;
    const size_t XB_BYTES = (size_t)N_TOK * DIM * 2;         // 64 MiB
    int mode = (ws_size >= XB_OFF + XB_BYTES) ? 2 : 0;
    unsigned short* wt = (mode == 2) ? (unsigned short*)(ws + WT_OFF) : nullptr;
    unsigned short* xb = (mode == 2) ? (unsigned short*)(ws + XB_OFF) : nullptr;

    hipMemsetAsync(ws, 0, 2048, stream);

    prep_kernel<<<dim3(512 + ((mode == 2) ? 2048 : 0)), 256, 0, stream>>>(
        x, gw, gb, ew, sel, nflag, flags, counts, xb, wt);
    gate_fix_kernel<<<dim3(16384), 64, 0, stream>>>(x, gw, gb, sel, nflag, flags, counts);
    sched_kernel<<<dim3(1), 64, 0, stream>>>(counts, offsets, schedE, schedR, totalRB,
                                             (mode == 2) ? 8 : 7);
    scatter_kernel<<<dim3(N_TOK / 256), 256, 0, stream>>>(sel, offsets, cursor, perm);

    if (mode == 2)
        moe_gemm7<<<dim3(1536), 512, 0, stream>>>(xb, wt, eb, perm, offsets, counts,
                                                  schedE, schedR, totalRB, out);
    else
        moe_gemm_legacy<<<dim3(320, 8), 256, 0, stream>>>(x, ew, eb, perm, offsets, counts,
                                                          schedE, schedR, totalRB, out);
}